// Round 1
// baseline (2652.884 us; speedup 1.0000x reference)
//
#include <hip/hip_runtime.h>

#define T_SEQ 2048
#define HDIM  128
#define GDIM  512
#define BATCH 256

typedef _Float16 f16;
typedef _Float16 f16x2 __attribute__((ext_vector_type(2)));
typedef _Float16 f16x8 __attribute__((ext_vector_type(8)));

#if __has_builtin(__builtin_amdgcn_fdot2)
__device__ __forceinline__ float dot2(f16x2 a, f16x2 b, float c) {
    return __builtin_amdgcn_fdot2(a, b, c, false);
}
#else
__device__ __forceinline__ float dot2(f16x2 a, f16x2 b, float c) {
    return c + (float)a[0] * (float)b[0] + (float)a[1] * (float)b[1];
}
#endif

__device__ __forceinline__ f16x2 mk2(float a, float b) {
    f16x2 r; r[0] = (f16)a; r[1] = (f16)b; return r;
}
// extract half2 pair m (0..3) from an 8-wide f16 vector (free after inlining:
// f16x8 = 4 VGPRs, each VGPR is exactly one f16x2)
__device__ __forceinline__ f16x2 pr(f16x8 v, int m) {
    f16x2 r; r[0] = v[2 * m]; r[1] = v[2 * m + 1]; return r;
}

__device__ __forceinline__ float sigm(float x) {
    return __builtin_amdgcn_rcpf(1.0f + __expf(-x));
}
// tanh(x) = 1 - 2/(e^{2x}+1); exp overflow -> rcp(inf)=0 -> +/-1 saturation is exact
__device__ __forceinline__ float tanh_fast(float x) {
    float e = __expf(2.0f * x);
    return 1.0f - 2.0f * __builtin_amdgcn_rcpf(e + 1.0f);
}

// One block per batch element. 512 threads: thread t owns gate-row t of
// W_hh_l0 (regs, f16), gate-row t of W_ih_l1 (regs, f16), gate-row t of
// W_hh_l1 (k<64 in regs, k>=64 in LDS). Layers are software-pipelined:
// iteration i computes layer0 step i and layer1 step i-1 concurrently
// (both consume the same LDS-resident h0 state).
__global__ __launch_bounds__(512, 2)
void lstm_fused(const float* __restrict__ x,
                const float* __restrict__ Wih0,
                const float* __restrict__ Whh0,
                const float* __restrict__ bih0,
                const float* __restrict__ bhh0,
                const float* __restrict__ Wih1,
                const float* __restrict__ Whh1,
                const float* __restrict__ bih1,
                const float* __restrict__ bhh1,
                const float* __restrict__ Wfc,
                const float* __restrict__ bfc,
                float* __restrict__ out)
{
    // W_hh_l1 high-k half: 512 rows x 64 halves, padded to 72 halves/row
    // (144 B = 9*16 B) so lane-t b128 reads stripe all 32 banks. 72 KB.
    __shared__ __align__(16) f16   wh1s[GDIM * 72];
    __shared__ __align__(16) float xs[T_SEQ];       // whole x[b,:] (8 KB)
    __shared__ __align__(16) f16   h0h[HDIM];       // h0 state, f16 (dot input)
    __shared__ __align__(16) f16   h1h[HDIM];       // h1 state, f16
    __shared__ float h0f[HDIM], h1f[HDIM];          // fp32 copies for outputs
    __shared__ float g0[GDIM], g1[GDIM];            // gate preactivations

    const int t = threadIdx.x;
    const int b = blockIdx.x;

    // stage the full input sequence for this batch element (coalesced)
    ((float4*)xs)[t] = ((const float4*)(x + (size_t)b * T_SEQ))[t];

    // ---- load per-thread weights into registers (f16-packed) ----
    f16x2 w0[64];  // W_hh_l0[t, 0:128]
    f16x2 wi[64];  // W_ih_l1[t, 0:128]
    f16x2 wl[32];  // W_hh_l1[t, 0:64]
    {
        const float4* p0 = (const float4*)(Whh0 + t * HDIM);
        const float4* p1 = (const float4*)(Wih1 + t * HDIM);
        const float4* p2 = (const float4*)(Whh1 + t * HDIM);
#pragma unroll
        for (int c = 0; c < 32; ++c) {
            float4 v = p0[c];
            w0[2 * c]     = mk2(v.x, v.y);
            w0[2 * c + 1] = mk2(v.z, v.w);
        }
#pragma unroll
        for (int c = 0; c < 32; ++c) {
            float4 v = p1[c];
            wi[2 * c]     = mk2(v.x, v.y);
            wi[2 * c + 1] = mk2(v.z, v.w);
        }
#pragma unroll
        for (int c = 0; c < 16; ++c) {
            float4 v = p2[c];
            wl[2 * c]     = mk2(v.x, v.y);
            wl[2 * c + 1] = mk2(v.z, v.w);
        }
        // W_hh_l1[t, 64:128] -> LDS (padded rows)
        f16x2* dst = (f16x2*)(wh1s + t * 72);
#pragma unroll
        for (int c = 0; c < 16; ++c) {
            float4 v = p2[16 + c];
            dst[2 * c]     = mk2(v.x, v.y);
            dst[2 * c + 1] = mk2(v.z, v.w);
        }
    }
    const float wx0   = Wih0[t];            // W_ih_l0 is [512,1]
    const float bias0 = bih0[t] + bhh0[t];
    const float bias1 = bih1[t] + bhh1[t];

    if (t < HDIM) {
        h0h[t] = (f16)0.f; h1h[t] = (f16)0.f;
        h0f[t] = 0.f;      h1f[t] = 0.f;
    }
    float c0r = 0.f, c1r = 0.f;  // cell state lives in its update thread
    __syncthreads();

    const f16x8* h0p  = (const f16x8*)h0h;
    const f16x8* h1p  = (const f16x8*)h1h;
    const f16x8* wrow = (const f16x8*)(wh1s + t * 72);

    for (int i = 0; i <= T_SEQ; ++i) {
        // ---- compute phase: all 512 threads, 192 dot2 each ----
        float a0 = (i < T_SEQ ? xs[i] : 0.f) * wx0 + bias0;
        float a1 = bias1;
#pragma unroll
        for (int c = 0; c < 16; ++c) {          // k = 0..127 of h0 (broadcast)
            f16x8 h = h0p[c];
#pragma unroll
            for (int m = 0; m < 4; ++m) {
                f16x2 hp = pr(h, m);
                a0 = dot2(w0[4 * c + m], hp, a0);   // layer0 recurrence
                a1 = dot2(wi[4 * c + m], hp, a1);   // layer1 input matvec
            }
        }
#pragma unroll
        for (int c = 0; c < 8; ++c) {           // k = 0..63 of h1, reg weights
            f16x8 h = h1p[c];
#pragma unroll
            for (int m = 0; m < 4; ++m)
                a1 = dot2(wl[4 * c + m], pr(h, m), a1);
        }
#pragma unroll
        for (int c = 0; c < 8; ++c) {           // k = 64..127 of h1, LDS weights
            f16x8 h = h1p[8 + c];
            f16x8 w = wrow[c];
#pragma unroll
            for (int m = 0; m < 4; ++m)
                a1 = dot2(pr(w, m), pr(h, m), a1);
        }
        g0[t] = a0;
        g1[t] = a1;
        __syncthreads();

        // ---- update phase: waves 0-1 -> layer0 unit t, waves 2-3 -> layer1 ----
        if (t < 128) {
            if (i < T_SEQ) {
                float gi = sigm(g0[t]);
                float gf = sigm(g0[t + 128]);
                float gg = tanh_fast(g0[t + 256]);
                float go = sigm(g0[t + 384]);
                c0r = gf * c0r + gi * gg;
                float h = go * tanh_fast(c0r);
                h0h[t] = (f16)h;
                h0f[t] = h;
            }
        } else if (t < 256) {
            if (i >= 1) {
                int j = t - 128;
                float gi = sigm(g1[j]);
                float gf = sigm(g1[j + 128]);
                float gg = tanh_fast(g1[j + 256]);
                float go = sigm(g1[j + 384]);
                c1r = gf * c1r + gi * gg;
                float h = go * tanh_fast(c1r);
                h1h[j] = (f16)h;
                h1f[j] = h;
            }
        }
        __syncthreads();
    }

    // ---- outputs: out = [ y(256) | h_n(2*256*128) | c_n(2*256*128) ] ----
    float* hn = out + BATCH;
    float* cn = out + BATCH + 2 * BATCH * HDIM;
    if (t < 128) {
        hn[(size_t)b * HDIM + t] = h0f[t];
        cn[(size_t)b * HDIM + t] = c0r;
    } else if (t < 256) {
        int j = t - 128;
        hn[BATCH * HDIM + (size_t)b * HDIM + j] = h1f[j];
        cn[BATCH * HDIM + (size_t)b * HDIM + j] = c1r;
    }
    // y[b] = h1_final . W_fc + b_fc  (wave 0 reduction)
    if (t < 64) {
        float p = h1f[t] * Wfc[t] + h1f[t + 64] * Wfc[t + 64];
#pragma unroll
        for (int o = 32; o >= 1; o >>= 1) p += __shfl_down(p, o);
        if (t == 0) out[b] = p + bfc[0];
    }
}

extern "C" void kernel_launch(void* const* d_in, const int* in_sizes, int n_in,
                              void* d_out, int out_size, void* d_ws, size_t ws_size,
                              hipStream_t stream) {
    const float* x    = (const float*)d_in[0];
    const float* Wih0 = (const float*)d_in[1];
    const float* Whh0 = (const float*)d_in[2];
    const float* bih0 = (const float*)d_in[3];
    const float* bhh0 = (const float*)d_in[4];
    const float* Wih1 = (const float*)d_in[5];
    const float* Whh1 = (const float*)d_in[6];
    const float* bih1 = (const float*)d_in[7];
    const float* bhh1 = (const float*)d_in[8];
    const float* Wfc  = (const float*)d_in[9];
    const float* bfc  = (const float*)d_in[10];
    lstm_fused<<<BATCH, 512, 0, stream>>>(x, Wih0, Whh0, bih0, bhh0,
                                          Wih1, Whh1, bih1, bhh1,
                                          Wfc, bfc, (float*)d_out);
}